// Round 1
// baseline (315.702 us; speedup 1.0000x reference)
//
#include <hip/hip_runtime.h>
#include <math.h>

// Problem constants
#define MM 4
#define BB 256
#define KK 64
#define HH 1024
#define NN 50
#define EE 1225
#define PP 64
#define CTOT 1375   // E + N*3

__device__ __forceinline__ float logsigm(float l) {
    // log sigmoid(-l) = -(max(l,0) + log1p(exp(-|l|)))
    return -(fmaxf(l, 0.0f) + log1pf(expf(-fabsf(l))));
}

__device__ __forceinline__ float wsum64(float v) {
    #pragma unroll
    for (int m = 1; m < 64; m <<= 1) v += __shfl_xor(v, m);
    return v;
}
__device__ __forceinline__ float wmax64(float v) {
    #pragma unroll
    for (int m = 1; m < 64; m <<= 1) v = fmaxf(v, __shfl_xor(v, m));
    return v;
}

// K1: h = relu(Z @ W1 + b1), Z = mean + exp(0.5*logvar)*eps
// grid 256 (one block per b), 256 threads. Also zero-inits Sneg.
__global__ __launch_bounds__(256) void k1(const float* __restrict__ mean,
                                          const float* __restrict__ logvar,
                                          const float* __restrict__ eps,
                                          const float* __restrict__ W1,
                                          const float* __restrict__ b1,
                                          float* __restrict__ h,
                                          float* __restrict__ Sneg) {
    const int b = blockIdx.x;
    const int t = threadIdx.x;
    __shared__ float4 z4[64];   // z4[k] = (z_m0, z_m1, z_m2, z_m3)
    if (t < 64) {
        float mv = mean[b * 64 + t];
        float lv = logvar[b * 64 + t];
        float sd = expf(0.5f * lv);
        float4 z;
        z.x = mv + sd * eps[(0 * BB + b) * 64 + t];
        z.y = mv + sd * eps[(1 * BB + b) * 64 + t];
        z.z = mv + sd * eps[(2 * BB + b) * 64 + t];
        z.w = mv + sd * eps[(3 * BB + b) * 64 + t];
        z4[t] = z;
    }
    if (t < 4) Sneg[b * 4 + t] = 0.0f;
    __syncthreads();
    #pragma unroll
    for (int jj = 0; jj < 4; jj++) {
        int j = jj * 256 + t;
        float s0 = 0.f, s1 = 0.f, s2 = 0.f, s3 = 0.f;
        #pragma unroll 8
        for (int k = 0; k < 64; k++) {
            float w = W1[k * HH + j];
            float4 z = z4[k];
            s0 += z.x * w; s1 += z.y * w; s2 += z.z * w; s3 += z.w * w;
        }
        float bb = b1[j];
        h[(b * 4 + 0) * HH + j] = fmaxf(s0 + bb, 0.f);
        h[(b * 4 + 1) * HH + j] = fmaxf(s1 + bb, 0.f);
        h[(b * 4 + 2) * HH + j] = fmaxf(s2 + bb, 0.f);
        h[(b * 4 + 3) * HH + j] = fmaxf(s3 + bb, 0.f);
    }
}

// K2: logits = h @ [WA | WF] + [bA | bF]  (rows = b*4+m, cols = 1375)
// Tile: 32 rows (8 graphs x 4 m) x 128 cols, K-chunk 32.
// Thread (rb = t/32, cg = t%32) owns rows 4rb..4rb+3 (one graph, all 4 m)
// and cols 4cg..4cg+3 -> Lbar needs no cross-thread reduction.
// Epilogue: Lbar[b,e] = mean_m logits; Sneg[b,m] += sum_e logsig(-l); store Fx logits.
__global__ __launch_bounds__(256) void k2(const float* __restrict__ h,
                                          const float* __restrict__ WA,
                                          const float* __restrict__ bA,
                                          const float* __restrict__ WF,
                                          const float* __restrict__ bF,
                                          float* __restrict__ Lbar,
                                          float* __restrict__ Sneg,
                                          float* __restrict__ lgF) {
    const int ct = blockIdx.x;   // 0..10 col tile
    const int bg = blockIdx.y;   // 0..31 row group (8 graphs)
    const int t  = threadIdx.x;
    const int rb = t >> 5;       // 0..7
    const int cg = t & 31;       // 0..31
    __shared__ float hs[32][33];
    __shared__ float was[32][128];
    float acc[4][4] = {};
    const int row0 = bg * 32;
    const int col0 = ct * 128;

    for (int ch = 0; ch < 32; ch++) {
        __syncthreads();
        #pragma unroll
        for (int i = 0; i < 4; i++) {
            int x = t + i * 256;
            int rr = x >> 5, kk = x & 31;
            hs[rr][kk] = h[(row0 + rr) * HH + ch * 32 + kk];
        }
        #pragma unroll
        for (int i = 0; i < 16; i++) {
            int x = t + i * 256;
            int kk = x >> 7, c = x & 127;
            int gc = col0 + c;
            int gk = ch * 32 + kk;
            float v = 0.f;
            if (gc < EE)        v = WA[gk * EE + gc];
            else if (gc < CTOT) v = WF[gk * 150 + (gc - EE)];
            was[kk][c] = v;
        }
        __syncthreads();
        #pragma unroll
        for (int kk = 0; kk < 32; kk++) {
            float4 w4 = *(const float4*)&was[kk][cg * 4];
            float h0 = hs[rb * 4 + 0][kk];
            float h1 = hs[rb * 4 + 1][kk];
            float h2 = hs[rb * 4 + 2][kk];
            float h3 = hs[rb * 4 + 3][kk];
            acc[0][0] += h0 * w4.x; acc[0][1] += h0 * w4.y; acc[0][2] += h0 * w4.z; acc[0][3] += h0 * w4.w;
            acc[1][0] += h1 * w4.x; acc[1][1] += h1 * w4.y; acc[1][2] += h1 * w4.z; acc[1][3] += h1 * w4.w;
            acc[2][0] += h2 * w4.x; acc[2][1] += h2 * w4.y; acc[2][2] += h2 * w4.z; acc[2][3] += h2 * w4.w;
            acc[3][0] += h3 * w4.x; acc[3][1] += h3 * w4.y; acc[3][2] += h3 * w4.z; acc[3][3] += h3 * w4.w;
        }
    }

    const int b = bg * 8 + rb;
    float sn0 = 0.f, sn1 = 0.f, sn2 = 0.f, sn3 = 0.f;
    #pragma unroll
    for (int cc = 0; cc < 4; cc++) {
        int gc = col0 + cg * 4 + cc;
        if (gc < EE) {
            float bias = bA[gc];
            float l0 = acc[0][cc] + bias, l1 = acc[1][cc] + bias;
            float l2 = acc[2][cc] + bias, l3 = acc[3][cc] + bias;
            Lbar[b * EE + gc] = 0.25f * (l0 + l1 + l2 + l3);
            sn0 += logsigm(l0); sn1 += logsigm(l1); sn2 += logsigm(l2); sn3 += logsigm(l3);
        } else if (gc < CTOT) {
            int c2 = gc - EE;
            float bias = bF[c2];
            #pragma unroll
            for (int m = 0; m < 4; m++) lgF[(b * 4 + m) * 150 + c2] = acc[m][cc] + bias;
        }
    }
    // reduce each sn over the 32 lanes sharing this graph (lanes 0..31 / 32..63 of wave)
    #pragma unroll
    for (int msk = 1; msk < 32; msk <<= 1) {
        sn0 += __shfl_xor(sn0, msk);
        sn1 += __shfl_xor(sn1, msk);
        sn2 += __shfl_xor(sn2, msk);
        sn3 += __shfl_xor(sn3, msk);
    }
    if ((t & 31) == 0) {
        atomicAdd(&Sneg[b * 4 + 0], sn0);
        atomicAdd(&Sneg[b * 4 + 1], sn1);
        atomicAdd(&Sneg[b * 4 + 2], sn2);
        atomicAdd(&Sneg[b * 4 + 3], sn3);
    }
}

// K4: per-graph finalization. grid 256, 256 threads (4 waves).
__global__ __launch_bounds__(256) void k4(const float* __restrict__ mean,
                                          const float* __restrict__ logvar,
                                          const float* __restrict__ A,
                                          const float* __restrict__ Fx,
                                          const float* __restrict__ coeff,
                                          const int* __restrict__ perms,
                                          const float* __restrict__ Lbar,
                                          const float* __restrict__ Sneg,
                                          const float* __restrict__ lgF,
                                          float* __restrict__ out) {
    const int b = blockIdx.x;
    const int t = threadIdx.x;
    const int w = t >> 6, lane = t & 63;
    __shared__ int   ip[PP * NN];     // inverse permutations
    __shared__ float Lb[EE];
    __shared__ int   edges[1280];
    __shared__ float lgfs[600];
    __shared__ int   nE;
    __shared__ float mred[4], wmaxs[4], klds;

    if (t == 0) nE = 0;
    for (int x = t; x < PP * NN; x += 256) {
        int p = x / NN, i = x - p * NN;
        ip[p * NN + perms[x]] = i;
    }
    for (int x = t; x < EE; x += 256) Lb[x] = Lbar[b * EE + x];
    for (int x = t; x < 600; x += 256) lgfs[x] = lgF[b * 600 + x];
    __syncthreads();

    // extract edges from lower triangle of A_in[b]
    for (int e = t; e < EE; e += 256) {
        int i = (int)((1.0f + sqrtf(8.0f * (float)e + 1.0f)) * 0.5f);
        while (i * (i - 1) / 2 > e) i--;
        while (i * (i + 1) / 2 <= e) i++;
        int j = e - i * (i - 1) / 2;
        float a = A[b * 2500 + i * NN + j];
        if (a != 0.0f) { int id = atomicAdd(&nE, 1); edges[id] = (i << 8) | j; }
    }

    // Fx terms: wave w handles sample m = w
    {
        float l0 = 0.f, l1 = 0.f, l2 = -INFINITY, x0 = 0.f, x1 = 0.f, x2 = 0.f;
        bool v = lane < NN;
        if (v) {
            l0 = lgfs[w * 150 + lane * 3 + 0];
            l1 = lgfs[w * 150 + lane * 3 + 1];
            l2 = lgfs[w * 150 + lane * 3 + 2];
            x0 = Fx[b * 150 + lane * 3 + 0];
            x1 = Fx[b * 150 + lane * 3 + 1];
            x2 = Fx[b * 150 + lane * 3 + 2];
        }
        float mx = wmax64(l2);
        float es = v ? expf(l2 - mx) : 0.f;
        es = wsum64(es);
        float lse = mx + logf(es);
        float val = 0.f;
        if (v) {
            val = coeff[0] * (logsigm(l0) + x0 * l0)
                + coeff[1] * (logsigm(l1) + x1 * l1)
                + coeff[2] * (x2 * (l2 - lse));
        }
        val = wsum64(val);
        if (lane == 0) mred[w] = val;
    }
    // KLD on wave 0 (K=64 -> one lane per dim)
    if (w == 0) {
        float lv = logvar[b * 64 + lane];
        float mn = mean[b * 64 + lane];
        float term = 0.5f * (expf(lv) + mn * mn - 1.0f - lv);
        term = wsum64(term);
        if (lane == 0) klds = term;
    }
    __syncthreads();

    const int ne = nE;
    float lmax = -INFINITY;
    for (int p = w; p < PP; p += 4) {
        const int* ipp = &ip[p * NN];
        float acc = 0.f;
        for (int x = lane; x < ne; x += 64) {
            int ed = edges[x];
            int iu = ipp[ed >> 8], iv = ipp[ed & 255];
            int ii = max(iu, iv), jj = min(iu, iv);
            acc += Lb[ii * (ii - 1) / 2 + jj];
        }
        acc = wsum64(acc);
        lmax = fmaxf(lmax, acc);
    }
    if (lane == 0) wmaxs[w] = lmax;
    __syncthreads();
    if (t == 0) {
        float dmax = fmaxf(fmaxf(wmaxs[0], wmaxs[1]), fmaxf(wmaxs[2], wmaxs[3]));
        float sbar = 0.25f * (Sneg[b * 4 + 0] + Sneg[b * 4 + 1] + Sneg[b * 4 + 2] + Sneg[b * 4 + 3]);
        float fxv  = 0.25f * (mred[0] + mred[1] + mred[2] + mred[3]);
        out[b] = (sbar + dmax) + fxv - klds;   // COEFF_A = 1, BETA = 1
    }
}

extern "C" void kernel_launch(void* const* d_in, const int* in_sizes, int n_in,
                              void* d_out, int out_size, void* d_ws, size_t ws_size,
                              hipStream_t stream) {
    const float* mean   = (const float*)d_in[0];
    const float* logvar = (const float*)d_in[1];
    const float* eps    = (const float*)d_in[2];
    const float* W1     = (const float*)d_in[3];
    const float* b1     = (const float*)d_in[4];
    const float* WA     = (const float*)d_in[5];
    const float* bA     = (const float*)d_in[6];
    const float* WF     = (const float*)d_in[7];
    const float* bF     = (const float*)d_in[8];
    const float* A      = (const float*)d_in[9];
    const float* Fx     = (const float*)d_in[10];
    const float* coeff  = (const float*)d_in[11];
    const int*   perms  = (const int*)d_in[12];
    float* out = (float*)d_out;

    float* ws   = (float*)d_ws;
    float* h    = ws;                  // 1024*1024
    float* Lbar = h + 1024 * 1024;     // 256*1225
    float* Sneg = Lbar + BB * EE;      // 1024 (zeroed by k1)
    float* lgF  = Sneg + 1024;         // 1024*150

    k1<<<dim3(BB), dim3(256), 0, stream>>>(mean, logvar, eps, W1, b1, h, Sneg);
    k2<<<dim3(11, 32), dim3(256), 0, stream>>>(h, WA, bA, WF, bF, Lbar, Sneg, lgF);
    k4<<<dim3(BB), dim3(256), 0, stream>>>(mean, logvar, A, Fx, coeff, perms, Lbar, Sneg, lgF, out);
}

// Round 2
// 155.459 us; speedup vs baseline: 2.0308x; 2.0308x over previous
//
#include <hip/hip_runtime.h>
#include <math.h>

// Problem constants
#define MM 4
#define BB 256
#define KK 64
#define HH 1024
#define NN 50
#define EE 1225
#define PP 64
#define CTOT 1375   // E + N*3
#define NPAD 1408   // cols padded to 11*128

typedef short short8 __attribute__((ext_vector_type(8)));
typedef float floatx4 __attribute__((ext_vector_type(4)));
typedef unsigned short ushort;

__device__ __forceinline__ ushort f2bf(float f) {
    union { float f; unsigned u; } v; v.f = f;
    unsigned r = v.u + 0x7fffu + ((v.u >> 16) & 1u);
    return (ushort)(r >> 16);
}

__device__ __forceinline__ float logsigm(float l) {
    // log sigmoid(-l) = -(max(l,0) + log1p(exp(-|l|)))
    return -(fmaxf(l, 0.0f) + log1pf(expf(-fabsf(l))));
}

__device__ __forceinline__ float wsum64(float v) {
    #pragma unroll
    for (int m = 1; m < 64; m <<= 1) v += __shfl_xor(v, m);
    return v;
}
__device__ __forceinline__ float wmax64(float v) {
    #pragma unroll
    for (int m = 1; m < 64; m <<= 1) v = fmaxf(v, __shfl_xor(v, m));
    return v;
}

// K0: Wt[n][k] (bf16, n<1408, k<1024) = transpose of [WA | WF], pad cols = 0.
// grid (16 k-tiles, 22 n-tiles), 256 threads. LDS float tile 64x65 (conflict-free).
__global__ __launch_bounds__(256) void k0(const float* __restrict__ WA,
                                          const float* __restrict__ WF,
                                          ushort* __restrict__ Wt) {
    const int kt = blockIdx.x, nt = blockIdx.y, t = threadIdx.x;
    __shared__ float T[64][65];
    const int k0 = kt * 64, n0 = nt * 64;
    #pragma unroll
    for (int i = 0; i < 16; i++) {
        int x = i * 256 + t;
        int kk = x >> 6, nn = x & 63;
        int gn = n0 + nn, gk = k0 + kk;
        float v = 0.f;
        if (gn < EE)        v = WA[gk * EE + gn];
        else if (gn < CTOT) v = WF[gk * 150 + (gn - EE)];
        T[kk][nn] = v;
    }
    __syncthreads();
    #pragma unroll
    for (int i = 0; i < 16; i++) {
        int x = i * 256 + t;
        int nn = x >> 6, kk = x & 63;
        Wt[(n0 + nn) * 1024 + k0 + kk] = f2bf(T[kk][nn]);
    }
}

// K1: h = relu(Z @ W1 + b1) stored as bf16 row-major [1024][1024].
// grid 256 (one block per b), 256 threads. Also zero-inits Sneg.
__global__ __launch_bounds__(256) void k1(const float* __restrict__ mean,
                                          const float* __restrict__ logvar,
                                          const float* __restrict__ eps,
                                          const float* __restrict__ W1,
                                          const float* __restrict__ b1,
                                          ushort* __restrict__ hB,
                                          float* __restrict__ Sneg) {
    const int b = blockIdx.x;
    const int t = threadIdx.x;
    __shared__ float4 z4[64];
    if (t < 64) {
        float mv = mean[b * 64 + t];
        float lv = logvar[b * 64 + t];
        float sd = expf(0.5f * lv);
        float4 z;
        z.x = mv + sd * eps[(0 * BB + b) * 64 + t];
        z.y = mv + sd * eps[(1 * BB + b) * 64 + t];
        z.z = mv + sd * eps[(2 * BB + b) * 64 + t];
        z.w = mv + sd * eps[(3 * BB + b) * 64 + t];
        z4[t] = z;
    }
    if (t < 4) Sneg[b * 4 + t] = 0.0f;
    __syncthreads();
    #pragma unroll
    for (int jj = 0; jj < 4; jj++) {
        int j = jj * 256 + t;
        float s0 = 0.f, s1 = 0.f, s2 = 0.f, s3 = 0.f;
        #pragma unroll 8
        for (int k = 0; k < 64; k++) {
            float w = W1[k * HH + j];
            float4 z = z4[k];
            s0 += z.x * w; s1 += z.y * w; s2 += z.z * w; s3 += z.w * w;
        }
        float bb = b1[j];
        hB[(b * 4 + 0) * HH + j] = f2bf(fmaxf(s0 + bb, 0.f));
        hB[(b * 4 + 1) * HH + j] = f2bf(fmaxf(s1 + bb, 0.f));
        hB[(b * 4 + 2) * HH + j] = f2bf(fmaxf(s2 + bb, 0.f));
        hB[(b * 4 + 3) * HH + j] = f2bf(fmaxf(s3 + bb, 0.f));
    }
}

// K2: MFMA GEMM logits[1024][1375] = hB @ Wt^T with fused epilogue.
// Block tile 64 rows x 128 cols, 4 waves (2x2), wave tile 32x64 = 2x4 MFMA 16x16x32.
// C/D layout: col = lane&15, row = quad*4 + reg -> each lane's 4 acc regs are one
// graph's 4 m-samples at one column.
__global__ __launch_bounds__(256) void k2(const ushort* __restrict__ hB,
                                          const ushort* __restrict__ Wt,
                                          const float* __restrict__ bA,
                                          const float* __restrict__ bF,
                                          float* __restrict__ Lbar,
                                          float* __restrict__ Sneg,
                                          float* __restrict__ lgF) {
    const int ct = blockIdx.x;   // 0..10
    const int rt = blockIdx.y;   // 0..15
    const int t = threadIdx.x;
    const int w = t >> 6, lane = t & 63;
    const int wm = w >> 1, wn = w & 1;
    const int quad = lane >> 4, l16 = lane & 15;
    __shared__ short As[64][72];
    __shared__ short Bs[128][72];
    floatx4 acc[2][4] = {};
    const int row0 = rt * 64, col0 = ct * 128;

    for (int ch = 0; ch < 16; ch++) {
        __syncthreads();
        #pragma unroll
        for (int i = 0; i < 2; i++) {
            int x = i * 256 + t;
            int r = x >> 3, ko = (x & 7) * 8;
            short8 v = *(const short8*)&hB[(row0 + r) * 1024 + ch * 64 + ko];
            *(short8*)&As[r][ko] = v;
        }
        #pragma unroll
        for (int i = 0; i < 4; i++) {
            int x = i * 256 + t;
            int r = x >> 3, ko = (x & 7) * 8;
            short8 v = *(const short8*)&Wt[(col0 + r) * 1024 + ch * 64 + ko];
            *(short8*)&Bs[r][ko] = v;
        }
        __syncthreads();
        #pragma unroll
        for (int kk = 0; kk < 2; kk++) {
            int ko = kk * 32 + quad * 8;
            short8 a0 = *(const short8*)&As[wm * 32 + l16][ko];
            short8 a1 = *(const short8*)&As[wm * 32 + 16 + l16][ko];
            short8 b0 = *(const short8*)&Bs[wn * 64 + l16][ko];
            short8 b1 = *(const short8*)&Bs[wn * 64 + 16 + l16][ko];
            short8 b2 = *(const short8*)&Bs[wn * 64 + 32 + l16][ko];
            short8 b3 = *(const short8*)&Bs[wn * 64 + 48 + l16][ko];
            acc[0][0] = __builtin_amdgcn_mfma_f32_16x16x32_bf16(a0, b0, acc[0][0], 0, 0, 0);
            acc[0][1] = __builtin_amdgcn_mfma_f32_16x16x32_bf16(a0, b1, acc[0][1], 0, 0, 0);
            acc[0][2] = __builtin_amdgcn_mfma_f32_16x16x32_bf16(a0, b2, acc[0][2], 0, 0, 0);
            acc[0][3] = __builtin_amdgcn_mfma_f32_16x16x32_bf16(a0, b3, acc[0][3], 0, 0, 0);
            acc[1][0] = __builtin_amdgcn_mfma_f32_16x16x32_bf16(a1, b0, acc[1][0], 0, 0, 0);
            acc[1][1] = __builtin_amdgcn_mfma_f32_16x16x32_bf16(a1, b1, acc[1][1], 0, 0, 0);
            acc[1][2] = __builtin_amdgcn_mfma_f32_16x16x32_bf16(a1, b2, acc[1][2], 0, 0, 0);
            acc[1][3] = __builtin_amdgcn_mfma_f32_16x16x32_bf16(a1, b3, acc[1][3], 0, 0, 0);
        }
    }

    // Epilogue
    #pragma unroll
    for (int mi = 0; mi < 2; mi++) {
        const int grow = row0 + wm * 32 + mi * 16 + quad * 4; // rows grow..grow+3 = graph b, m=0..3
        const int b = grow >> 2;
        float sn0 = 0.f, sn1 = 0.f, sn2 = 0.f, sn3 = 0.f;
        #pragma unroll
        for (int ni = 0; ni < 4; ni++) {
            int gc = col0 + wn * 64 + ni * 16 + l16;
            floatx4 a = acc[mi][ni];
            if (gc < EE) {
                float bias = bA[gc];
                float l0 = a[0] + bias, l1 = a[1] + bias, l2 = a[2] + bias, l3 = a[3] + bias;
                Lbar[b * EE + gc] = 0.25f * (l0 + l1 + l2 + l3);
                sn0 += logsigm(l0); sn1 += logsigm(l1); sn2 += logsigm(l2); sn3 += logsigm(l3);
            } else if (gc < CTOT) {
                int c2 = gc - EE;
                float bias = bF[c2];
                lgF[(b * 4 + 0) * 150 + c2] = a[0] + bias;
                lgF[(b * 4 + 1) * 150 + c2] = a[1] + bias;
                lgF[(b * 4 + 2) * 150 + c2] = a[2] + bias;
                lgF[(b * 4 + 3) * 150 + c2] = a[3] + bias;
            }
        }
        #pragma unroll
        for (int msk = 1; msk < 16; msk <<= 1) {
            sn0 += __shfl_xor(sn0, msk);
            sn1 += __shfl_xor(sn1, msk);
            sn2 += __shfl_xor(sn2, msk);
            sn3 += __shfl_xor(sn3, msk);
        }
        if (l16 == 0) {
            atomicAdd(&Sneg[b * 4 + 0], sn0);
            atomicAdd(&Sneg[b * 4 + 1], sn1);
            atomicAdd(&Sneg[b * 4 + 2], sn2);
            atomicAdd(&Sneg[b * 4 + 3], sn3);
        }
    }
}

// K4: per-graph finalization. grid 256, 256 threads (4 waves).
__global__ __launch_bounds__(256) void k4(const float* __restrict__ mean,
                                          const float* __restrict__ logvar,
                                          const float* __restrict__ A,
                                          const float* __restrict__ Fx,
                                          const float* __restrict__ coeff,
                                          const int* __restrict__ perms,
                                          const float* __restrict__ Lbar,
                                          const float* __restrict__ Sneg,
                                          const float* __restrict__ lgF,
                                          float* __restrict__ out) {
    const int b = blockIdx.x;
    const int t = threadIdx.x;
    const int w = t >> 6, lane = t & 63;
    __shared__ int   ip[PP * NN];
    __shared__ float Lb[EE];
    __shared__ int   edges[1280];
    __shared__ float lgfs[600];
    __shared__ int   nE;
    __shared__ float mred[4], wmaxs[4], klds;

    if (t == 0) nE = 0;
    for (int x = t; x < PP * NN; x += 256) {
        int p = x / NN, i = x - p * NN;
        ip[p * NN + perms[x]] = i;
    }
    for (int x = t; x < EE; x += 256) Lb[x] = Lbar[b * EE + x];
    for (int x = t; x < 600; x += 256) lgfs[x] = lgF[b * 600 + x];
    __syncthreads();

    for (int e = t; e < EE; e += 256) {
        int i = (int)((1.0f + sqrtf(8.0f * (float)e + 1.0f)) * 0.5f);
        while (i * (i - 1) / 2 > e) i--;
        while (i * (i + 1) / 2 <= e) i++;
        int j = e - i * (i - 1) / 2;
        float a = A[b * 2500 + i * NN + j];
        if (a != 0.0f) { int id = atomicAdd(&nE, 1); edges[id] = (i << 8) | j; }
    }

    {
        float l0 = 0.f, l1 = 0.f, l2 = -INFINITY, x0 = 0.f, x1 = 0.f, x2 = 0.f;
        bool v = lane < NN;
        if (v) {
            l0 = lgfs[w * 150 + lane * 3 + 0];
            l1 = lgfs[w * 150 + lane * 3 + 1];
            l2 = lgfs[w * 150 + lane * 3 + 2];
            x0 = Fx[b * 150 + lane * 3 + 0];
            x1 = Fx[b * 150 + lane * 3 + 1];
            x2 = Fx[b * 150 + lane * 3 + 2];
        }
        float mx = wmax64(l2);
        float es = v ? expf(l2 - mx) : 0.f;
        es = wsum64(es);
        float lse = mx + logf(es);
        float val = 0.f;
        if (v) {
            val = coeff[0] * (logsigm(l0) + x0 * l0)
                + coeff[1] * (logsigm(l1) + x1 * l1)
                + coeff[2] * (x2 * (l2 - lse));
        }
        val = wsum64(val);
        if (lane == 0) mred[w] = val;
    }
    if (w == 0) {
        float lv = logvar[b * 64 + lane];
        float mn = mean[b * 64 + lane];
        float term = 0.5f * (expf(lv) + mn * mn - 1.0f - lv);
        term = wsum64(term);
        if (lane == 0) klds = term;
    }
    __syncthreads();

    const int ne = nE;
    float lmax = -INFINITY;
    for (int p = w; p < PP; p += 4) {
        const int* ipp = &ip[p * NN];
        float acc = 0.f;
        for (int x = lane; x < ne; x += 64) {
            int ed = edges[x];
            int iu = ipp[ed >> 8], iv = ipp[ed & 255];
            int ii = max(iu, iv), jj = min(iu, iv);
            acc += Lb[ii * (ii - 1) / 2 + jj];
        }
        acc = wsum64(acc);
        lmax = fmaxf(lmax, acc);
    }
    if (lane == 0) wmaxs[w] = lmax;
    __syncthreads();
    if (t == 0) {
        float dmax = fmaxf(fmaxf(wmaxs[0], wmaxs[1]), fmaxf(wmaxs[2], wmaxs[3]));
        float sbar = 0.25f * (Sneg[b * 4 + 0] + Sneg[b * 4 + 1] + Sneg[b * 4 + 2] + Sneg[b * 4 + 3]);
        float fxv  = 0.25f * (mred[0] + mred[1] + mred[2] + mred[3]);
        out[b] = (sbar + dmax) + fxv - klds;
    }
}

extern "C" void kernel_launch(void* const* d_in, const int* in_sizes, int n_in,
                              void* d_out, int out_size, void* d_ws, size_t ws_size,
                              hipStream_t stream) {
    const float* mean   = (const float*)d_in[0];
    const float* logvar = (const float*)d_in[1];
    const float* eps    = (const float*)d_in[2];
    const float* W1     = (const float*)d_in[3];
    const float* b1     = (const float*)d_in[4];
    const float* WA     = (const float*)d_in[5];
    const float* bA     = (const float*)d_in[6];
    const float* WF     = (const float*)d_in[7];
    const float* bF     = (const float*)d_in[8];
    const float* A      = (const float*)d_in[9];
    const float* Fx     = (const float*)d_in[10];
    const float* coeff  = (const float*)d_in[11];
    const int*   perms  = (const int*)d_in[12];
    float* out = (float*)d_out;

    ushort* Wt  = (ushort*)d_ws;               // 1408*1024 bf16
    ushort* hB  = Wt + NPAD * 1024;            // 1024*1024 bf16
    float*  Lbar = (float*)(hB + 1024 * 1024); // 256*1225
    float*  Sneg = Lbar + BB * EE;             // 1024 (zeroed by k1)
    float*  lgF  = Sneg + 1024;                // 1024*150

    k0<<<dim3(16, 22), dim3(256), 0, stream>>>(WA, WF, Wt);
    k1<<<dim3(BB), dim3(256), 0, stream>>>(mean, logvar, eps, W1, b1, hB, Sneg);
    k2<<<dim3(11, 16), dim3(256), 0, stream>>>(hB, Wt, bA, bF, Lbar, Sneg, lgF);
    k4<<<dim3(BB), dim3(256), 0, stream>>>(mean, logvar, A, Fx, coeff, perms, Lbar, Sneg, lgF, out);
}

// Round 3
// 138.290 us; speedup vs baseline: 2.2829x; 1.1242x over previous
//
#include <hip/hip_runtime.h>
#include <math.h>

// Problem constants
#define MM 4
#define BB 256
#define KK 64
#define HH 1024
#define NN 50
#define EE 1225
#define PP 64
#define CTOT 1375   // E + N*3
#define NPAD 1408   // cols padded to 11*128

typedef short short8 __attribute__((ext_vector_type(8)));
typedef float floatx4 __attribute__((ext_vector_type(4)));
typedef unsigned short ushort;

__device__ __forceinline__ ushort f2bf(float f) {
    union { float f; unsigned u; } v; v.f = f;
    unsigned r = v.u + 0x7fffu + ((v.u >> 16) & 1u);
    return (ushort)(r >> 16);
}

__device__ __forceinline__ float logsigm(float l) {
    // log sigmoid(-l) = -(max(l,0) + log1p(exp(-|l|)))
    return -(fmaxf(l, 0.0f) + log1pf(expf(-fabsf(l))));
}

__device__ __forceinline__ float wsum64(float v) {
    #pragma unroll
    for (int m = 1; m < 64; m <<= 1) v += __shfl_xor(v, m);
    return v;
}
__device__ __forceinline__ float wmax64(float v) {
    #pragma unroll
    for (int m = 1; m < 64; m <<= 1) v = fmaxf(v, __shfl_xor(v, m));
    return v;
}

// kA: fused k0 (weight transpose->bf16) + k1 (h = relu(Z@W1+b1) -> bf16).
// Blocks 0..255: k1 for graph b=blockIdx.x. Blocks 256..607: k0 tile (16 kt x 22 nt).
__global__ __launch_bounds__(256) void kA(const float* __restrict__ mean,
                                          const float* __restrict__ logvar,
                                          const float* __restrict__ eps,
                                          const float* __restrict__ W1,
                                          const float* __restrict__ b1,
                                          const float* __restrict__ WA,
                                          const float* __restrict__ WF,
                                          ushort* __restrict__ hB,
                                          ushort* __restrict__ Wt,
                                          float* __restrict__ Sneg) {
    const int t = threadIdx.x;
    __shared__ float smem[64 * 65];

    if (blockIdx.x < 256) {
        // ---- k1: reparam + relu GEMM for graph b ----
        const int b = blockIdx.x;
        float4* z4 = (float4*)smem;
        if (t < 64) {
            float mv = mean[b * 64 + t];
            float lv = logvar[b * 64 + t];
            float sd = expf(0.5f * lv);
            float4 z;
            z.x = mv + sd * eps[(0 * BB + b) * 64 + t];
            z.y = mv + sd * eps[(1 * BB + b) * 64 + t];
            z.z = mv + sd * eps[(2 * BB + b) * 64 + t];
            z.w = mv + sd * eps[(3 * BB + b) * 64 + t];
            z4[t] = z;
        }
        if (t < 4) Sneg[b * 4 + t] = 0.0f;
        __syncthreads();
        const int j0 = t * 4;
        float acc[4][4] = {};   // [m][jc]
        #pragma unroll 8
        for (int k = 0; k < 64; k++) {
            float4 w = *(const float4*)&W1[k * HH + j0];
            float4 z = z4[k];
            acc[0][0] += z.x * w.x; acc[0][1] += z.x * w.y; acc[0][2] += z.x * w.z; acc[0][3] += z.x * w.w;
            acc[1][0] += z.y * w.x; acc[1][1] += z.y * w.y; acc[1][2] += z.y * w.z; acc[1][3] += z.y * w.w;
            acc[2][0] += z.z * w.x; acc[2][1] += z.z * w.y; acc[2][2] += z.z * w.z; acc[2][3] += z.z * w.w;
            acc[3][0] += z.w * w.x; acc[3][1] += z.w * w.y; acc[3][2] += z.w * w.z; acc[3][3] += z.w * w.w;
        }
        float4 bb = *(const float4*)&b1[j0];
        #pragma unroll
        for (int m = 0; m < 4; m++) {
            unsigned u0 = ((unsigned)f2bf(fmaxf(acc[m][0] + bb.x, 0.f))) |
                          ((unsigned)f2bf(fmaxf(acc[m][1] + bb.y, 0.f)) << 16);
            unsigned u1 = ((unsigned)f2bf(fmaxf(acc[m][2] + bb.z, 0.f))) |
                          ((unsigned)f2bf(fmaxf(acc[m][3] + bb.w, 0.f)) << 16);
            uint2 u; u.x = u0; u.y = u1;
            *(uint2*)&hB[(b * 4 + m) * HH + j0] = u;
        }
    } else {
        // ---- k0: Wt[n][k] = transpose of [WA | WF] (bf16, zero-padded cols) ----
        const int id = blockIdx.x - 256;
        const int kt = id & 15, nt = id >> 4;
        float* T = smem;   // [64][65]
        const int k0 = kt * 64, n0 = nt * 64;
        #pragma unroll
        for (int i = 0; i < 16; i++) {
            int x = i * 256 + t;
            int kk = x >> 6, nn = x & 63;
            int gn = n0 + nn, gk = k0 + kk;
            float v = 0.f;
            if (gn < EE)        v = WA[gk * EE + gn];
            else if (gn < CTOT) v = WF[gk * 150 + (gn - EE)];
            T[kk * 65 + nn] = v;
        }
        __syncthreads();
        #pragma unroll
        for (int i = 0; i < 16; i++) {
            int x = i * 256 + t;
            int nn = x >> 6, kk = x & 63;
            Wt[(n0 + nn) * 1024 + k0 + kk] = f2bf(T[kk * 65 + nn]);
        }
    }
}

// K2: MFMA GEMM logits[1024][1375] = hB @ Wt^T with fused epilogue + register
// double-buffer prefetch (global loads for chunk ch+1 in flight during MFMA on ch).
// Block tile 64 rows x 128 cols, 4 waves (2x2), wave tile 32x64 = 2x4 MFMA 16x16x32.
__global__ __launch_bounds__(256) void k2(const ushort* __restrict__ hB,
                                          const ushort* __restrict__ Wt,
                                          const float* __restrict__ bA,
                                          const float* __restrict__ bF,
                                          float* __restrict__ Lbar,
                                          float* __restrict__ Sneg,
                                          float* __restrict__ lgF) {
    const int ct = blockIdx.x;   // 0..10
    const int rt = blockIdx.y;   // 0..15
    const int t = threadIdx.x;
    const int w = t >> 6, lane = t & 63;
    const int wm = w >> 1, wn = w & 1;
    const int quad = lane >> 4, l16 = lane & 15;
    __shared__ short As[64][72];
    __shared__ short Bs[128][72];
    floatx4 acc[2][4] = {};
    const int row0 = rt * 64, col0 = ct * 128;

    // per-thread staging coordinates (fixed across chunks)
    const int rA0 = t >> 3,              koA = (t & 7) * 8;        // i=0
    const int rA1 = (256 + t) >> 3;                                 // i=1 (same ko)
    const int rB0 = t >> 3;                                         // B rows: i*32 + (t>>3)
    const ushort* pA0 = hB + (row0 + rA0) * 1024 + koA;
    const ushort* pA1 = hB + (row0 + rA1) * 1024 + koA;
    const ushort* pB  = Wt + (col0 + rB0) * 1024 + koA;

    short8 ra[2], rb[4];
    // prologue: load chunk 0
    ra[0] = *(const short8*)(pA0);
    ra[1] = *(const short8*)(pA1);
    #pragma unroll
    for (int i = 0; i < 4; i++) rb[i] = *(const short8*)(pB + i * 32 * 1024);

    for (int ch = 0; ch < 16; ch++) {
        __syncthreads();   // previous iteration's LDS reads complete
        *(short8*)&As[rA0][koA] = ra[0];
        *(short8*)&As[rA1][koA] = ra[1];
        #pragma unroll
        for (int i = 0; i < 4; i++) *(short8*)&Bs[i * 32 + rB0][koA] = rb[i];
        __syncthreads();
        if (ch < 15) {
            const int off = (ch + 1) * 64;
            ra[0] = *(const short8*)(pA0 + off);
            ra[1] = *(const short8*)(pA1 + off);
            #pragma unroll
            for (int i = 0; i < 4; i++) rb[i] = *(const short8*)(pB + i * 32 * 1024 + off);
        }
        #pragma unroll
        for (int kk = 0; kk < 2; kk++) {
            int ko = kk * 32 + quad * 8;
            short8 a0 = *(const short8*)&As[wm * 32 + l16][ko];
            short8 a1 = *(const short8*)&As[wm * 32 + 16 + l16][ko];
            short8 b0 = *(const short8*)&Bs[wn * 64 + l16][ko];
            short8 b1 = *(const short8*)&Bs[wn * 64 + 16 + l16][ko];
            short8 b2 = *(const short8*)&Bs[wn * 64 + 32 + l16][ko];
            short8 b3 = *(const short8*)&Bs[wn * 64 + 48 + l16][ko];
            acc[0][0] = __builtin_amdgcn_mfma_f32_16x16x32_bf16(a0, b0, acc[0][0], 0, 0, 0);
            acc[0][1] = __builtin_amdgcn_mfma_f32_16x16x32_bf16(a0, b1, acc[0][1], 0, 0, 0);
            acc[0][2] = __builtin_amdgcn_mfma_f32_16x16x32_bf16(a0, b2, acc[0][2], 0, 0, 0);
            acc[0][3] = __builtin_amdgcn_mfma_f32_16x16x32_bf16(a0, b3, acc[0][3], 0, 0, 0);
            acc[1][0] = __builtin_amdgcn_mfma_f32_16x16x32_bf16(a1, b0, acc[1][0], 0, 0, 0);
            acc[1][1] = __builtin_amdgcn_mfma_f32_16x16x32_bf16(a1, b1, acc[1][1], 0, 0, 0);
            acc[1][2] = __builtin_amdgcn_mfma_f32_16x16x32_bf16(a1, b2, acc[1][2], 0, 0, 0);
            acc[1][3] = __builtin_amdgcn_mfma_f32_16x16x32_bf16(a1, b3, acc[1][3], 0, 0, 0);
        }
    }

    // Epilogue: C/D layout col=lane&15, row=quad*4+reg -> lane's 4 regs = graph b, m=0..3
    #pragma unroll
    for (int mi = 0; mi < 2; mi++) {
        const int grow = row0 + wm * 32 + mi * 16 + quad * 4;
        const int b = grow >> 2;
        float sn0 = 0.f, sn1 = 0.f, sn2 = 0.f, sn3 = 0.f;
        #pragma unroll
        for (int ni = 0; ni < 4; ni++) {
            int gc = col0 + wn * 64 + ni * 16 + l16;
            floatx4 a = acc[mi][ni];
            if (gc < EE) {
                float bias = bA[gc];
                float l0 = a[0] + bias, l1 = a[1] + bias, l2 = a[2] + bias, l3 = a[3] + bias;
                Lbar[b * EE + gc] = 0.25f * (l0 + l1 + l2 + l3);
                sn0 += logsigm(l0); sn1 += logsigm(l1); sn2 += logsigm(l2); sn3 += logsigm(l3);
            } else if (gc < CTOT) {
                int c2 = gc - EE;
                float bias = bF[c2];
                lgF[(b * 4 + 0) * 150 + c2] = a[0] + bias;
                lgF[(b * 4 + 1) * 150 + c2] = a[1] + bias;
                lgF[(b * 4 + 2) * 150 + c2] = a[2] + bias;
                lgF[(b * 4 + 3) * 150 + c2] = a[3] + bias;
            }
        }
        #pragma unroll
        for (int msk = 1; msk < 16; msk <<= 1) {
            sn0 += __shfl_xor(sn0, msk);
            sn1 += __shfl_xor(sn1, msk);
            sn2 += __shfl_xor(sn2, msk);
            sn3 += __shfl_xor(sn3, msk);
        }
        if (l16 == 0) {
            atomicAdd(&Sneg[b * 4 + 0], sn0);
            atomicAdd(&Sneg[b * 4 + 1], sn1);
            atomicAdd(&Sneg[b * 4 + 2], sn2);
            atomicAdd(&Sneg[b * 4 + 3], sn3);
        }
    }
}

// K4: per-graph finalization. grid 256, 256 threads (4 waves).
__global__ __launch_bounds__(256) void k4(const float* __restrict__ mean,
                                          const float* __restrict__ logvar,
                                          const float* __restrict__ A,
                                          const float* __restrict__ Fx,
                                          const float* __restrict__ coeff,
                                          const int* __restrict__ perms,
                                          const float* __restrict__ Lbar,
                                          const float* __restrict__ Sneg,
                                          const float* __restrict__ lgF,
                                          float* __restrict__ out) {
    const int b = blockIdx.x;
    const int t = threadIdx.x;
    const int w = t >> 6, lane = t & 63;
    __shared__ int   ip[PP * NN];
    __shared__ float Lb[EE];
    __shared__ int   edges[1280];
    __shared__ float lgfs[600];
    __shared__ int   nE;
    __shared__ float mred[4], wmaxs[4], klds;

    if (t == 0) nE = 0;
    for (int x = t; x < PP * NN; x += 256) {
        int p = x / NN, i = x - p * NN;
        ip[p * NN + perms[x]] = i;
    }
    for (int x = t; x < EE; x += 256) Lb[x] = Lbar[b * EE + x];
    for (int x = t; x < 600; x += 256) lgfs[x] = lgF[b * 600 + x];
    __syncthreads();

    for (int e = t; e < EE; e += 256) {
        int i = (int)((1.0f + sqrtf(8.0f * (float)e + 1.0f)) * 0.5f);
        while (i * (i - 1) / 2 > e) i--;
        while (i * (i + 1) / 2 <= e) i++;
        int j = e - i * (i - 1) / 2;
        float a = A[b * 2500 + i * NN + j];
        if (a != 0.0f) { int id = atomicAdd(&nE, 1); edges[id] = (i << 8) | j; }
    }

    {
        float l0 = 0.f, l1 = 0.f, l2 = -INFINITY, x0 = 0.f, x1 = 0.f, x2 = 0.f;
        bool v = lane < NN;
        if (v) {
            l0 = lgfs[w * 150 + lane * 3 + 0];
            l1 = lgfs[w * 150 + lane * 3 + 1];
            l2 = lgfs[w * 150 + lane * 3 + 2];
            x0 = Fx[b * 150 + lane * 3 + 0];
            x1 = Fx[b * 150 + lane * 3 + 1];
            x2 = Fx[b * 150 + lane * 3 + 2];
        }
        float mx = wmax64(l2);
        float es = v ? expf(l2 - mx) : 0.f;
        es = wsum64(es);
        float lse = mx + logf(es);
        float val = 0.f;
        if (v) {
            val = coeff[0] * (logsigm(l0) + x0 * l0)
                + coeff[1] * (logsigm(l1) + x1 * l1)
                + coeff[2] * (x2 * (l2 - lse));
        }
        val = wsum64(val);
        if (lane == 0) mred[w] = val;
    }
    if (w == 0) {
        float lv = logvar[b * 64 + lane];
        float mn = mean[b * 64 + lane];
        float term = 0.5f * (expf(lv) + mn * mn - 1.0f - lv);
        term = wsum64(term);
        if (lane == 0) klds = term;
    }
    __syncthreads();

    const int ne = nE;
    float lmax = -INFINITY;
    for (int p = w; p < PP; p += 4) {
        const int* ipp = &ip[p * NN];
        float acc = 0.f;
        for (int x = lane; x < ne; x += 64) {
            int ed = edges[x];
            int iu = ipp[ed >> 8], iv = ipp[ed & 255];
            int ii = max(iu, iv), jj = min(iu, iv);
            acc += Lb[ii * (ii - 1) / 2 + jj];
        }
        acc = wsum64(acc);
        lmax = fmaxf(lmax, acc);
    }
    if (lane == 0) wmaxs[w] = lmax;
    __syncthreads();
    if (t == 0) {
        float dmax = fmaxf(fmaxf(wmaxs[0], wmaxs[1]), fmaxf(wmaxs[2], wmaxs[3]));
        float sbar = 0.25f * (Sneg[b * 4 + 0] + Sneg[b * 4 + 1] + Sneg[b * 4 + 2] + Sneg[b * 4 + 3]);
        float fxv  = 0.25f * (mred[0] + mred[1] + mred[2] + mred[3]);
        out[b] = (sbar + dmax) + fxv - klds;
    }
}

extern "C" void kernel_launch(void* const* d_in, const int* in_sizes, int n_in,
                              void* d_out, int out_size, void* d_ws, size_t ws_size,
                              hipStream_t stream) {
    const float* mean   = (const float*)d_in[0];
    const float* logvar = (const float*)d_in[1];
    const float* eps    = (const float*)d_in[2];
    const float* W1     = (const float*)d_in[3];
    const float* b1     = (const float*)d_in[4];
    const float* WA     = (const float*)d_in[5];
    const float* bA     = (const float*)d_in[6];
    const float* WF     = (const float*)d_in[7];
    const float* bF     = (const float*)d_in[8];
    const float* A      = (const float*)d_in[9];
    const float* Fx     = (const float*)d_in[10];
    const float* coeff  = (const float*)d_in[11];
    const int*   perms  = (const int*)d_in[12];
    float* out = (float*)d_out;

    ushort* Wt  = (ushort*)d_ws;               // 1408*1024 bf16
    ushort* hB  = Wt + NPAD * 1024;            // 1024*1024 bf16
    float*  Lbar = (float*)(hB + 1024 * 1024); // 256*1225
    float*  Sneg = Lbar + BB * EE;             // 1024 (zeroed by kA)
    float*  lgF  = Sneg + 1024;                // 1024*150

    kA<<<dim3(608), dim3(256), 0, stream>>>(mean, logvar, eps, W1, b1, WA, WF, hB, Wt, Sneg);
    k2<<<dim3(11, 16), dim3(256), 0, stream>>>(hB, Wt, bA, bF, Lbar, Sneg, lgF);
    k4<<<dim3(BB), dim3(256), 0, stream>>>(mean, logvar, A, Fx, coeff, perms, Lbar, Sneg, lgF, out);
}